// Round 17
// baseline (148.540 us; speedup 1.0000x reference)
//
#include <hip/hip_runtime.h>
#include <hip/hip_bf16.h>

// Self-attention with softmax over the QUERY axis (dim=1):
//   Q=XWq^T K=XWk^T V=XWv^T ; s = QK^T/16 ; attn[:,q,k] = exp(s)/sum_q exp(s)
//   out = attn @ V
// B=4, S=4096, D=Q_DIM=256.
//
// Path A: materialize P=exp(s/16) bf16 in ws.
//   gemm_qkv: staged (global_load_lds, BK=64, vmcnt(8), fenced).
//   sp_kernel: 256x256 s-tile, 512 thr / 8 waves, BK=32 x 8 phases, staging
//     2x32KB aliased under swizzled Pt[256][256] (128KB LDS); halves staged
//     bytes vs 128x128 (537->268MB).
//   pv_gemm: 128q x 128v tile, 512 thr, BK=64, vmcnt(4), fenced, XCD swizzle.
// Path B: flash-style fallback.

#define BATCH 4
#define SEQ 4096
#define DIM 256
#define ROWS (BATCH * SEQ)   // 16384

typedef __bf16 bf16x8 __attribute__((ext_vector_type(8)));
typedef float f32x4 __attribute__((ext_vector_type(4)));

#define SB() __builtin_amdgcn_sched_barrier(0)

// ---------------- vectorized cast f32 -> bf16 (n multiple of 8) ----------------
__global__ void cast_v8(const float* __restrict__ in,
                        __bf16* __restrict__ out, int n8) {
    int i = blockIdx.x * blockDim.x + threadIdx.x;
    if (i >= n8) return;
    const float4 f0 = *(const float4*)(in + (size_t)i * 8);
    const float4 f1 = *(const float4*)(in + (size_t)i * 8 + 4);
    bf16x8 o;
    o[0] = (__bf16)f0.x; o[1] = (__bf16)f0.y; o[2] = (__bf16)f0.z; o[3] = (__bf16)f0.w;
    o[4] = (__bf16)f1.x; o[5] = (__bf16)f1.y; o[6] = (__bf16)f1.z; o[7] = (__bf16)f1.w;
    *(bf16x8*)(out + (size_t)i * 8) = o;
}

// weights: 3 arrays of 65536 cast in one launch
__global__ void cast_w3(const float* __restrict__ w0, const float* __restrict__ w1,
                        const float* __restrict__ w2, __bf16* __restrict__ o0,
                        __bf16* __restrict__ o1, __bf16* __restrict__ o2) {
    int t = blockIdx.x * blockDim.x + threadIdx.x;   // 3 * 8192
    int arr = t >> 13;
    int i = (t & 8191);
    const float* in = arr == 0 ? w0 : arr == 1 ? w1 : w2;
    __bf16* out = arr == 0 ? o0 : arr == 1 ? o1 : o2;
    const float4 f0 = *(const float4*)(in + (size_t)i * 8);
    const float4 f1 = *(const float4*)(in + (size_t)i * 8 + 4);
    bf16x8 o;
    o[0] = (__bf16)f0.x; o[1] = (__bf16)f0.y; o[2] = (__bf16)f0.z; o[3] = (__bf16)f0.w;
    o[4] = (__bf16)f1.x; o[5] = (__bf16)f1.y; o[6] = (__bf16)f1.z; o[7] = (__bf16)f1.w;
    *(bf16x8*)(out + (size_t)i * 8) = o;
}

// ------- QKV GEMM (staged): z=0 Q, z=1 K, z=2 V(transposed store). -------
__global__ __launch_bounds__(256) void gemm_qkv(const __bf16* __restrict__ X,
                                                const __bf16* __restrict__ Wq,
                                                const __bf16* __restrict__ Wk,
                                                const __bf16* __restrict__ Wv,
                                                __bf16* __restrict__ Qo,
                                                __bf16* __restrict__ Ko,
                                                __bf16* __restrict__ Vo) {
    __shared__ __bf16 smem[32768];   // [2][16384]: X 16KB | W 16KB per buf
    const int z = blockIdx.z;
    const __bf16* Wz = z == 0 ? Wq : z == 1 ? Wk : Wv;
    __bf16* outp = z == 0 ? Qo : z == 1 ? Ko : Vo;
    const int trans = (z == 2);

    const int t = threadIdx.x;
    const int w = t >> 6, l = t & 63;
    const int wr = w >> 1, wc = w & 1;
    const int lr = l & 15, lk = l >> 4;
    const int rb0 = blockIdx.x * 128;
    const int cb0 = blockIdx.y * 128;
    const int rbase = rb0 + wr * 64;
    const int cbase = cb0 + wc * 64;

    const int lrow = l >> 3;
    const int lslot = l & 7;
    const __bf16* src[8];
#pragma unroll
    for (int i = 0; i < 8; ++i) {
        const int chunk = i * 4 + w;
        if (chunk < 16) {
            const int xr = chunk * 8 + lrow;
            src[i] = X + (size_t)(rb0 + xr) * 256 + ((lslot ^ (xr & 7)) * 8);
        } else {
            const int wrr = (chunk - 16) * 8 + lrow;
            src[i] = Wz + (size_t)(cb0 + wrr) * 256 + ((lslot ^ (wrr & 7)) * 8);
        }
    }

#define GSTAGE(bi) do {                                                       \
        _Pragma("unroll")                                                     \
        for (int i_ = 0; i_ < 8; ++i_) {                                      \
            const int chunk_ = i_ * 4 + w;                                    \
            __builtin_amdgcn_global_load_lds(                                 \
                (const unsigned int*)src[i_],                                 \
                (unsigned int*)&smem[(bi) * 16384 + chunk_ * 512], 16, 0, 0); \
        }                                                                     \
    } while (0)
#define GADV() do { _Pragma("unroll") for (int x_ = 0; x_ < 8; ++x_) src[x_] += 64; } while (0)

#define GCOMPUTE(bi) do {                                                     \
        const char* A_ = (const char*)smem + (bi) * 32768;                    \
        const char* B_ = A_ + 16384;                                          \
        _Pragma("unroll")                                                     \
        for (int ks_ = 0; ks_ < 2; ++ks_) {                                   \
            bf16x8 af_[4], bf_[4];                                            \
            const int cb_ = ks_ * 64 + lk * 16;                               \
            _Pragma("unroll")                                                 \
            for (int i_ = 0; i_ < 4; ++i_) {                                  \
                const int row_ = wr * 64 + i_ * 16 + lr;                      \
                af_[i_] = *(const bf16x8*)(A_ + row_ * 128 +                  \
                                           (cb_ ^ ((row_ & 7) << 4)));        \
            }                                                                 \
            _Pragma("unroll")                                                 \
            for (int j_ = 0; j_ < 4; ++j_) {                                  \
                const int row_ = wc * 64 + j_ * 16 + lr;                      \
                bf_[j_] = *(const bf16x8*)(B_ + row_ * 128 +                  \
                                           (cb_ ^ ((row_ & 7) << 4)));        \
            }                                                                 \
            _Pragma("unroll")                                                 \
            for (int i_ = 0; i_ < 4; ++i_)                                    \
                _Pragma("unroll")                                             \
                for (int j_ = 0; j_ < 4; ++j_)                                \
                    acc[i_][j_] = __builtin_amdgcn_mfma_f32_16x16x32_bf16(    \
                        af_[i_], bf_[j_], acc[i_][j_], 0, 0, 0);              \
        }                                                                     \
    } while (0)

    f32x4 acc[4][4] = {};
    GSTAGE(0);
#pragma unroll 1
    for (int tt = 0; tt < 4; tt += 2) {
        GADV();
        GSTAGE(1);
        SB(); asm volatile("s_waitcnt vmcnt(8)" ::: "memory"); SB();
        __builtin_amdgcn_s_barrier(); SB();
        GCOMPUTE(0);
        SB(); __builtin_amdgcn_s_barrier(); SB();

        if (tt == 0) {
            GADV();
            GSTAGE(0);
            SB(); asm volatile("s_waitcnt vmcnt(8)" ::: "memory"); SB();
        } else {
            SB(); asm volatile("s_waitcnt vmcnt(0)" ::: "memory"); SB();
        }
        __builtin_amdgcn_s_barrier(); SB();
        GCOMPUTE(1);
        SB(); __builtin_amdgcn_s_barrier(); SB();
    }
#undef GSTAGE
#undef GADV
#undef GCOMPUTE

#pragma unroll
    for (int i = 0; i < 4; ++i)
#pragma unroll
        for (int j = 0; j < 4; ++j)
#pragma unroll
            for (int r = 0; r < 4; ++r) {
                int row = rbase + i * 16 + lk * 4 + r;
                int col = cbase + j * 16 + lr;
                __bf16 v = (__bf16)acc[i][j][r];
                if (!trans) outp[(size_t)row * DIM + col] = v;
                else        outp[(size_t)col * ROWS + row] = v;
            }
}

// ================= PATH A =================
// sp_kernel: s-tile 256q x 256k, 512 thr / 8 waves (2q x 4k), wave 128q x 64k.
// BK=32 x 8 phases; staging 2 x 32KB aliased under swizzled Pt (128KB LDS).
__global__ __launch_bounds__(512, 2) void sp_kernel(const __bf16* __restrict__ Qb,
                                                    const __bf16* __restrict__ Kb,
                                                    __bf16* __restrict__ P,
                                                    float* __restrict__ lsum) {
    __shared__ __bf16 smem[65536];   // 128KB: staging [2][16384] / swizzled Pt 256x256
    const int t = threadIdx.x;
    const int w = t >> 6, l = t & 63;
    const int wq = w >> 2, wk = w & 3;       // 2 q-halves x 4 k-quarters
    const int lr = l & 15, lk = l >> 4;
    const int b = blockIdx.z;
    const int kb0 = blockIdx.x * 256;
    const int qb0 = blockIdx.y * 256;
    const __bf16* Q = Qb + (size_t)b * SEQ * 256;
    const __bf16* K = Kb + (size_t)b * SEQ * 256;
    __bf16* Pb = P + (size_t)b * SEQ * SEQ;

    // staging: 32 chunks of 1KB (16 rows x 64B). chunks 0-15 = Q(256 rows),
    // 16-31 = K. wave w loads chunks {i*8+w}. swizzle slot^((row>>1)&3).
    const int lrow = l >> 2;       // row within 16-row chunk
    const int lslot = l & 3;       // 16B slot within 64B row
    const __bf16* src[4];
#pragma unroll
    for (int i = 0; i < 4; ++i) {
        const int chunk = i * 8 + w;
        if (chunk < 16) {
            const int qr = chunk * 16 + lrow;
            src[i] = Q + (size_t)(qb0 + qr) * 256 + ((lslot ^ ((qr >> 1) & 3)) * 8);
        } else {
            const int kr = (chunk - 16) * 16 + lrow;
            src[i] = K + (size_t)(kb0 + kr) * 256 + ((lslot ^ ((kr >> 1) & 3)) * 8);
        }
    }

#define SPSTAGE(bi) do {                                                      \
        _Pragma("unroll")                                                     \
        for (int i_ = 0; i_ < 4; ++i_) {                                      \
            const int chunk_ = i_ * 8 + w;                                    \
            __builtin_amdgcn_global_load_lds(                                 \
                (const unsigned int*)src[i_],                                 \
                (unsigned int*)&smem[(bi) * 16384 + chunk_ * 512], 16, 0, 0); \
        }                                                                     \
    } while (0)
#define SPADV() do { _Pragma("unroll") for (int x_ = 0; x_ < 4; ++x_) src[x_] += 32; } while (0)

#define SPCOMPUTE(bi) do {                                                    \
        const char* A_ = (const char*)smem + (bi) * 32768;                    \
        const char* B_ = A_ + 16384;                                          \
        bf16x8 af_[8], bf_[4];                                                \
        _Pragma("unroll")                                                     \
        for (int i_ = 0; i_ < 8; ++i_) {                                      \
            const int qr_ = wq * 128 + i_ * 16 + lr;                          \
            af_[i_] = *(const bf16x8*)(A_ + qr_ * 64 +                        \
                                       ((lk ^ ((qr_ >> 1) & 3)) * 16));       \
        }                                                                     \
        _Pragma("unroll")                                                     \
        for (int j_ = 0; j_ < 4; ++j_) {                                      \
            const int kr_ = wk * 64 + j_ * 16 + lr;                           \
            bf_[j_] = *(const bf16x8*)(B_ + kr_ * 64 +                        \
                                       ((lk ^ ((kr_ >> 1) & 3)) * 16));       \
        }                                                                     \
        _Pragma("unroll")                                                     \
        for (int i_ = 0; i_ < 8; ++i_)                                        \
            _Pragma("unroll")                                                 \
            for (int j_ = 0; j_ < 4; ++j_)                                    \
                acc[i_][j_] = __builtin_amdgcn_mfma_f32_16x16x32_bf16(        \
                    af_[i_], bf_[j_], acc[i_][j_], 0, 0, 0);                  \
    } while (0)

    f32x4 acc[8][4] = {};
    SPSTAGE(0);
#pragma unroll 1
    for (int tt = 0; tt < 8; tt += 2) {
        SPADV();
        SPSTAGE(1);
        SB(); asm volatile("s_waitcnt vmcnt(4)" ::: "memory"); SB();
        __builtin_amdgcn_s_barrier(); SB();
        SPCOMPUTE(0);
        SB(); __builtin_amdgcn_s_barrier(); SB();

        if (tt < 6) {
            SPADV();
            SPSTAGE(0);
            SB(); asm volatile("s_waitcnt vmcnt(4)" ::: "memory"); SB();
        } else {
            SB(); asm volatile("s_waitcnt vmcnt(0)" ::: "memory"); SB();
        }
        __builtin_amdgcn_s_barrier(); SB();
        SPCOMPUTE(1);
        SB(); __builtin_amdgcn_s_barrier(); SB();
    }
#undef SPSTAGE
#undef SPADV
#undef SPCOMPUTE

    // exp epilogue into swizzled Pt (aliases smem; staging consumed, barrier passed)
    // Pt byte = q*512 + ((2*k) ^ ((q&7)<<4))
    char* Pt = (char*)smem;
#pragma unroll
    for (int j = 0; j < 4; ++j) {
        float cs = 0.f;
#pragma unroll
        for (int i = 0; i < 8; ++i)
#pragma unroll
            for (int r = 0; r < 4; ++r) {
                float v = __expf(acc[i][j][r] * 0.0625f);
                cs += v;
                const int q = wq * 128 + i * 16 + lk * 4 + r;
                const int k = wk * 64 + j * 16 + lr;
                *(__bf16*)(Pt + q * 512 + ((2 * k) ^ ((q & 7) << 4))) = (__bf16)v;
            }
        cs += __shfl_xor(cs, 16, 64);
        cs += __shfl_xor(cs, 32, 64);
        if (lk == 0)
            atomicAdd(&lsum[(size_t)b * SEQ + kb0 + wk * 64 + j * 16 + lr], cs);
    }
    __syncthreads();
    // coalesced store: 256 rows x 32 chunks(16B), 16 iters x 512 thr
#pragma unroll
    for (int it = 0; it < 16; ++it) {
        int n = it * 512 + t;
        int row = n >> 5;
        int ch = n & 31;
        *(bf16x8*)(Pb + (size_t)(qb0 + row) * SEQ + kb0 + ch * 8) =
            *(const bf16x8*)(Pt + row * 512 + ((ch * 16) ^ ((row & 7) << 4)));
    }
}

// scale Vt rows by 1/l (vectorized x8): Vt[v][b*S+k] *= 1/l[b*S+k]
__global__ void scale_vt(__bf16* __restrict__ Vt,
                         const float* __restrict__ lsum, int n8) {
    int i = blockIdx.x * blockDim.x + threadIdx.x;
    if (i >= n8) return;
    int col8 = (i & (ROWS / 8 - 1)) * 8;
    bf16x8 d = *(const bf16x8*)(Vt + (size_t)i * 8);
#pragma unroll
    for (int j = 0; j < 8; ++j)
        d[j] = (__bf16)((float)d[j] / lsum[col8 + j]);
    *(bf16x8*)(Vt + (size_t)i * 8) = d;
}

// PV GEMM: out[q,v] = sum_k P[q,k] * Vt[v][b*S+k].  (P flat: [qglob][SEQ])
// Tile 128q x 128v, 512 thr = 8 waves (2q x 4v), wave-tile 64q x 32v.
// BK=64, 2x32KB dbuf, vmcnt(4), fenced. Grid 256 blocks 1D + XCD swizzle.
__global__ __launch_bounds__(512) void pv_gemm(const __bf16* __restrict__ P,
                                               const __bf16* __restrict__ Vt,
                                               float* __restrict__ out) {
    __shared__ __bf16 lds[32768];   // [2][16384]: A(P) 16KB | B(Vt) 16KB per buf
    const int t = threadIdx.x;
    const int w = t >> 6, l = t & 63;
    const int wq = w >> 2, wv = w & 3;       // 2q x 4v waves
    const int lr = l & 15, lk = l >> 4;

    const int fid = blockIdx.x;
    const int remap = (fid & 7) * 32 + (fid >> 3);
    const int vtile = remap >> 7;                // 0..1
    const int rowblk = remap & 127;              // 0..127
    const int row_blk = rowblk * 128;            // global q-row base
    const int b = rowblk >> 5;
    const int vbase = vtile * 128;
    const size_t bS = (size_t)b * SEQ;

    const int lrow = l >> 3;
    const int lslot = l & 7;
    const __bf16* src[4];
#pragma unroll
    for (int i = 0; i < 4; ++i) {
        const int chunk = i * 8 + w;             // 32 chunks over 8 waves
        if (chunk < 16) {
            const int arow = chunk * 8 + lrow;
            src[i] = P + (size_t)(row_blk + arow) * SEQ + ((lslot ^ (arow & 7)) * 8);
        } else {
            const int vrow = (chunk - 16) * 8 + lrow;
            src[i] = Vt + (size_t)(vbase + vrow) * ROWS + bS + ((lslot ^ (vrow & 7)) * 8);
        }
    }

#define STAGE(bi) do {                                                        \
        _Pragma("unroll")                                                     \
        for (int i_ = 0; i_ < 4; ++i_) {                                      \
            const int chunk_ = i_ * 8 + w;                                    \
            __builtin_amdgcn_global_load_lds(                                 \
                (const unsigned int*)src[i_],                                 \
                (unsigned int*)&lds[(bi) * 16384 + chunk_ * 512], 16, 0, 0);  \
        }                                                                     \
    } while (0)

#define ADV() do { _Pragma("unroll") for (int i_ = 0; i_ < 4; ++i_) src[i_] += 64; } while (0)

#define COMPUTE(bi) do {                                                      \
        const char* A_ = (const char*)lds + (bi) * 32768;                     \
        const char* B_ = A_ + 16384;                                          \
        _Pragma("unroll")                                                     \
        for (int ks_ = 0; ks_ < 2; ++ks_) {                                   \
            bf16x8 af_[4], bf_[2];                                            \
            const int cb_ = ks_ * 64 + lk * 16;                               \
            _Pragma("unroll")                                                 \
            for (int i_ = 0; i_ < 4; ++i_) {                                  \
                const int row_ = wq * 64 + i_ * 16 + lr;                      \
                af_[i_] = *(const bf16x8*)(A_ + row_ * 128 +                  \
                                           (cb_ ^ ((row_ & 7) << 4)));        \
            }                                                                 \
            _Pragma("unroll")                                                 \
            for (int j_ = 0; j_ < 2; ++j_) {                                  \
                const int row_ = wv * 32 + j_ * 16 + lr;                      \
                bf_[j_] = *(const bf16x8*)(B_ + row_ * 128 +                  \
                                           (cb_ ^ ((row_ & 7) << 4)));        \
            }                                                                 \
            _Pragma("unroll")                                                 \
            for (int i_ = 0; i_ < 4; ++i_)                                    \
                _Pragma("unroll")                                             \
                for (int j_ = 0; j_ < 2; ++j_)                                \
                    acc[i_][j_] = __builtin_amdgcn_mfma_f32_16x16x32_bf16(    \
                        af_[i_], bf_[j_], acc[i_][j_], 0, 0, 0);              \
        }                                                                     \
    } while (0)

    f32x4 acc[4][2] = {};
    STAGE(0);
#pragma unroll 1
    for (int tt = 0; tt < 64; tt += 2) {
        if (tt < 63) ADV();
        STAGE(1);
        SB(); asm volatile("s_waitcnt vmcnt(4)" ::: "memory"); SB();
        __builtin_amdgcn_s_barrier(); SB();
        COMPUTE(0);
        SB(); __builtin_amdgcn_s_barrier(); SB();

        if (tt + 1 < 63) ADV();
        STAGE(0);
        SB(); asm volatile("s_waitcnt vmcnt(4)" ::: "memory"); SB();
        __builtin_amdgcn_s_barrier(); SB();
        COMPUTE(1);
        SB(); __builtin_amdgcn_s_barrier(); SB();
    }
#undef STAGE
#undef ADV
#undef COMPUTE

#pragma unroll
    for (int i = 0; i < 4; ++i)
#pragma unroll
        for (int j = 0; j < 2; ++j)
#pragma unroll
            for (int r = 0; r < 4; ++r) {
                const int row = row_blk + wq * 64 + i * 16 + lk * 4 + r;
                const int col = vbase + wv * 32 + j * 16 + lr;
                out[(size_t)row * 256 + col] = acc[i][j][r];
            }
}

// ================= PATH B (fallback) =================
__global__ __launch_bounds__(256) void colsumexp(const __bf16* __restrict__ Qb,
                                                 const __bf16* __restrict__ Kb,
                                                 float* __restrict__ lsum) {
    const int l = threadIdx.x & 63;
    const int w = threadIdx.x >> 6;
    const int wr = w >> 1, wc = w & 1;
    const int lr = l & 15, lk = l >> 4;
    const int b = blockIdx.z;
    const int cbase = blockIdx.x * 128 + wc * 64;
    const __bf16* Q = Qb + (size_t)b * SEQ * 256;
    const __bf16* K = Kb + (size_t)b * SEQ * 256;

    float csum[4] = {0.f, 0.f, 0.f, 0.f};
    for (int qi = 0; qi < 16; ++qi) {
        const int rbase = blockIdx.y * 2048 + qi * 128 + wr * 64;
        f32x4 acc[4][4] = {};
#pragma unroll
        for (int d0 = 0; d0 < 256; d0 += 32) {
            bf16x8 a[4], bb[4];
#pragma unroll
            for (int i = 0; i < 4; ++i)
                a[i] = *(const bf16x8*)(Q + (size_t)(rbase + i * 16 + lr) * 256 + d0 + lk * 8);
#pragma unroll
            for (int j = 0; j < 4; ++j)
                bb[j] = *(const bf16x8*)(K + (size_t)(cbase + j * 16 + lr) * 256 + d0 + lk * 8);
#pragma unroll
            for (int i = 0; i < 4; ++i)
#pragma unroll
                for (int j = 0; j < 4; ++j)
                    acc[i][j] = __builtin_amdgcn_mfma_f32_16x16x32_bf16(a[i], bb[j], acc[i][j], 0, 0, 0);
        }
#pragma unroll
        for (int j = 0; j < 4; ++j) {
            float s = 0.f;
#pragma unroll
            for (int i = 0; i < 4; ++i)
#pragma unroll
                for (int r = 0; r < 4; ++r)
                    s += __expf(acc[i][j][r] * 0.0625f);
            csum[j] += s;
        }
    }
#pragma unroll
    for (int j = 0; j < 4; ++j) {
        float s = csum[j];
        s += __shfl_xor(s, 16, 64);
        s += __shfl_xor(s, 32, 64);
        if (lk == 0)
            atomicAdd(&lsum[(size_t)b * SEQ + cbase + j * 16 + lr], s);
    }
}

__global__ __launch_bounds__(256) void pv_kernel(const __bf16* __restrict__ Qb,
                                                 const __bf16* __restrict__ Kb,
                                                 const __bf16* __restrict__ Vt,
                                                 float* __restrict__ out) {
    __shared__ __bf16 Pl[128][72];
    const int l = threadIdx.x & 63;
    const int w = threadIdx.x >> 6;
    const int wr = w >> 1, wc = w & 1;
    const int lr = l & 15, lk = l >> 4;
    const int b = blockIdx.z;
    const int qbase = blockIdx.x * 128;
    const int vbase = blockIdx.y * 128;
    const __bf16* Q = Qb + (size_t)b * SEQ * 256;
    const __bf16* K = Kb + (size_t)b * SEQ * 256;
    const __bf16* V = Vt + (size_t)b * SEQ;

    f32x4 oacc[4][4] = {};
    for (int k0 = 0; k0 < SEQ; k0 += 64) {
        f32x4 sacc[4][2] = {};
#pragma unroll
        for (int d0 = 0; d0 < 256; d0 += 32) {
            bf16x8 a[4], bb[2];
#pragma unroll
            for (int i = 0; i < 4; ++i)
                a[i] = *(const bf16x8*)(Q + (size_t)(qbase + wr * 64 + i * 16 + lr) * 256 + d0 + lk * 8);
#pragma unroll
            for (int j = 0; j < 2; ++j)
                bb[j] = *(const bf16x8*)(K + (size_t)(k0 + wc * 32 + j * 16 + lr) * 256 + d0 + lk * 8);
#pragma unroll
            for (int i = 0; i < 4; ++i)
#pragma unroll
                for (int j = 0; j < 2; ++j)
                    sacc[i][j] = __builtin_amdgcn_mfma_f32_16x16x32_bf16(a[i], bb[j], sacc[i][j], 0, 0, 0);
        }
#pragma unroll
        for (int i = 0; i < 4; ++i)
#pragma unroll
            for (int j = 0; j < 2; ++j)
#pragma unroll
                for (int r = 0; r < 4; ++r)
                    Pl[wr * 64 + i * 16 + lk * 4 + r][wc * 32 + j * 16 + lr] =
                        (__bf16)__expf(sacc[i][j][r] * 0.0625f);
        __syncthreads();
#pragma unroll
        for (int ks = 0; ks < 2; ++ks) {
            bf16x8 a[4], bb[4];
#pragma unroll
            for (int i = 0; i < 4; ++i)
                a[i] = *(const bf16x8*)(&Pl[wr * 64 + i * 16 + lr][ks * 32 + lk * 8]);
#pragma unroll
            for (int j = 0; j < 4; ++j)
                bb[j] = *(const bf16x8*)(V + (size_t)(vbase + wc * 64 + j * 16 + lr) * ROWS + k0 + ks * 32 + lk * 8);
#pragma unroll
            for (int i = 0; i < 4; ++i)
#pragma unroll
                for (int j = 0; j < 4; ++j)
                    oacc[i][j] = __builtin_amdgcn_mfma_f32_16x16x32_bf16(a[i], bb[j], oacc[i][j], 0, 0, 0);
        }
        __syncthreads();
    }
    float* O = out + (size_t)b * SEQ * 256;
#pragma unroll
    for (int i = 0; i < 4; ++i)
#pragma unroll
        for (int j = 0; j < 4; ++j)
#pragma unroll
            for (int r = 0; r < 4; ++r) {
                int row = qbase + wr * 64 + i * 16 + lk * 4 + r;
                int col = vbase + wc * 64 + j * 16 + lr;
                O[(size_t)row * 256 + col] = oacc[i][j][r];
            }
}

extern "C" void kernel_launch(void* const* d_in, const int* in_sizes, int n_in,
                              void* d_out, int out_size, void* d_ws, size_t ws_size,
                              hipStream_t stream) {
    const float* x  = (const float*)d_in[0];
    const float* wq = (const float*)d_in[1];
    const float* wk = (const float*)d_in[2];
    const float* wv = (const float*)d_in[3];
    float* out = (float*)d_out;

    char* ws = (char*)d_ws;
    __bf16* Xb  = (__bf16*)(ws + 0);
    __bf16* Qb  = (__bf16*)(ws + 8388608);
    __bf16* Kb  = (__bf16*)(ws + 16777216);
    __bf16* Vt  = (__bf16*)(ws + 25165824);
    __bf16* Wqb = (__bf16*)(ws + 33554432);
    __bf16* Wkb = (__bf16*)(ws + 33685504);
    __bf16* Wvb = (__bf16*)(ws + 33816576);
    float*  lsum = (float*)(ws + 33947648);
    __bf16* Pbuf = (__bf16*)(ws + 34013184);
    const size_t need_A = 34013184 + (size_t)BATCH * SEQ * SEQ * 2;   // ~168 MB

    const int n_x = ROWS * DIM;      // 4194304

    cast_v8<<<(n_x / 8 + 255) / 256, 256, 0, stream>>>(x, Xb, n_x / 8);
    cast_w3<<<(3 * 8192 + 255) / 256, 256, 0, stream>>>(wq, wk, wv, Wqb, Wkb, Wvb);

    dim3 gg(ROWS / 128, DIM / 128, 3);   // (128, 2, 3)
    gemm_qkv<<<gg, 256, 0, stream>>>(Xb, Wqb, Wkb, Wvb, Qb, Kb, Vt);

    hipMemsetAsync(lsum, 0, (size_t)BATCH * SEQ * sizeof(float), stream);

    if (ws_size >= need_A) {
        dim3 gs(SEQ / 256, SEQ / 256, BATCH);   // (16, 16, 4) = 1024 blocks
        sp_kernel<<<gs, 512, 0, stream>>>(Qb, Kb, Pbuf, lsum);
        scale_vt<<<(n_x / 8 + 255) / 256, 256, 0, stream>>>(Vt, lsum, n_x / 8);
        pv_gemm<<<256, 512, 0, stream>>>(Pbuf, Vt, out);   // 128x128 tile, 8 waves
    } else {
        dim3 gs(SEQ / 128, 2, BATCH);
        colsumexp<<<gs, 256, 0, stream>>>(Qb, Kb, lsum);
        scale_vt<<<(n_x / 8 + 255) / 256, 256, 0, stream>>>(Vt, lsum, n_x / 8);
        dim3 gp(SEQ / 128, DIM / 128, BATCH);
        pv_kernel<<<gp, 256, 0, stream>>>(Qb, Kb, Vt, out);
    }
}

// Round 18
// 139.954 us; speedup vs baseline: 1.0614x; 1.0614x over previous
//
#include <hip/hip_runtime.h>
#include <hip/hip_bf16.h>

// Self-attention with softmax over the QUERY axis (dim=1):
//   Q=XWq^T K=XWk^T V=XWv^T ; s = QK^T/16 ; attn[:,q,k] = exp(s)/sum_q exp(s)
//   out = attn @ V
// B=4, S=4096, D=Q_DIM=256.
//
// Path A: materialize P=exp(s/16) bf16 in ws.
//   gemm_qkv: staged (global_load_lds, BK=64, vmcnt(8), fenced).
//   sp_kernel: 256q x 128k s-tile, 512 thr / 8 waves (4q x 2k, wave 64x64),
//     BK=32 x 8 phases, staging 2x24KB aliased under Pt[256][136] (69.6KB LDS
//     -> 2 blocks/CU); staged bytes 537->403MB.
//   pv_gemm: 128q x 128v tile, 512 thr, BK=64, vmcnt(4), fenced, XCD swizzle.
// Path B: flash-style fallback.

#define BATCH 4
#define SEQ 4096
#define DIM 256
#define ROWS (BATCH * SEQ)   // 16384

typedef __bf16 bf16x8 __attribute__((ext_vector_type(8)));
typedef float f32x4 __attribute__((ext_vector_type(4)));

#define SB() __builtin_amdgcn_sched_barrier(0)

// ---------------- vectorized cast f32 -> bf16 (n multiple of 8) ----------------
__global__ void cast_v8(const float* __restrict__ in,
                        __bf16* __restrict__ out, int n8) {
    int i = blockIdx.x * blockDim.x + threadIdx.x;
    if (i >= n8) return;
    const float4 f0 = *(const float4*)(in + (size_t)i * 8);
    const float4 f1 = *(const float4*)(in + (size_t)i * 8 + 4);
    bf16x8 o;
    o[0] = (__bf16)f0.x; o[1] = (__bf16)f0.y; o[2] = (__bf16)f0.z; o[3] = (__bf16)f0.w;
    o[4] = (__bf16)f1.x; o[5] = (__bf16)f1.y; o[6] = (__bf16)f1.z; o[7] = (__bf16)f1.w;
    *(bf16x8*)(out + (size_t)i * 8) = o;
}

// weights: 3 arrays of 65536 cast in one launch
__global__ void cast_w3(const float* __restrict__ w0, const float* __restrict__ w1,
                        const float* __restrict__ w2, __bf16* __restrict__ o0,
                        __bf16* __restrict__ o1, __bf16* __restrict__ o2) {
    int t = blockIdx.x * blockDim.x + threadIdx.x;   // 3 * 8192
    int arr = t >> 13;
    int i = (t & 8191);
    const float* in = arr == 0 ? w0 : arr == 1 ? w1 : w2;
    __bf16* out = arr == 0 ? o0 : arr == 1 ? o1 : o2;
    const float4 f0 = *(const float4*)(in + (size_t)i * 8);
    const float4 f1 = *(const float4*)(in + (size_t)i * 8 + 4);
    bf16x8 o;
    o[0] = (__bf16)f0.x; o[1] = (__bf16)f0.y; o[2] = (__bf16)f0.z; o[3] = (__bf16)f0.w;
    o[4] = (__bf16)f1.x; o[5] = (__bf16)f1.y; o[6] = (__bf16)f1.z; o[7] = (__bf16)f1.w;
    *(bf16x8*)(out + (size_t)i * 8) = o;
}

// ------- QKV GEMM (staged): z=0 Q, z=1 K, z=2 V(transposed store). -------
__global__ __launch_bounds__(256) void gemm_qkv(const __bf16* __restrict__ X,
                                                const __bf16* __restrict__ Wq,
                                                const __bf16* __restrict__ Wk,
                                                const __bf16* __restrict__ Wv,
                                                __bf16* __restrict__ Qo,
                                                __bf16* __restrict__ Ko,
                                                __bf16* __restrict__ Vo) {
    __shared__ __bf16 smem[32768];   // [2][16384]: X 16KB | W 16KB per buf
    const int z = blockIdx.z;
    const __bf16* Wz = z == 0 ? Wq : z == 1 ? Wk : Wv;
    __bf16* outp = z == 0 ? Qo : z == 1 ? Ko : Vo;
    const int trans = (z == 2);

    const int t = threadIdx.x;
    const int w = t >> 6, l = t & 63;
    const int wr = w >> 1, wc = w & 1;
    const int lr = l & 15, lk = l >> 4;
    const int rb0 = blockIdx.x * 128;
    const int cb0 = blockIdx.y * 128;
    const int rbase = rb0 + wr * 64;
    const int cbase = cb0 + wc * 64;

    const int lrow = l >> 3;
    const int lslot = l & 7;
    const __bf16* src[8];
#pragma unroll
    for (int i = 0; i < 8; ++i) {
        const int chunk = i * 4 + w;
        if (chunk < 16) {
            const int xr = chunk * 8 + lrow;
            src[i] = X + (size_t)(rb0 + xr) * 256 + ((lslot ^ (xr & 7)) * 8);
        } else {
            const int wrr = (chunk - 16) * 8 + lrow;
            src[i] = Wz + (size_t)(cb0 + wrr) * 256 + ((lslot ^ (wrr & 7)) * 8);
        }
    }

#define GSTAGE(bi) do {                                                       \
        _Pragma("unroll")                                                     \
        for (int i_ = 0; i_ < 8; ++i_) {                                      \
            const int chunk_ = i_ * 4 + w;                                    \
            __builtin_amdgcn_global_load_lds(                                 \
                (const unsigned int*)src[i_],                                 \
                (unsigned int*)&smem[(bi) * 16384 + chunk_ * 512], 16, 0, 0); \
        }                                                                     \
    } while (0)
#define GADV() do { _Pragma("unroll") for (int x_ = 0; x_ < 8; ++x_) src[x_] += 64; } while (0)

#define GCOMPUTE(bi) do {                                                     \
        const char* A_ = (const char*)smem + (bi) * 32768;                    \
        const char* B_ = A_ + 16384;                                          \
        _Pragma("unroll")                                                     \
        for (int ks_ = 0; ks_ < 2; ++ks_) {                                   \
            bf16x8 af_[4], bf_[4];                                            \
            const int cb_ = ks_ * 64 + lk * 16;                               \
            _Pragma("unroll")                                                 \
            for (int i_ = 0; i_ < 4; ++i_) {                                  \
                const int row_ = wr * 64 + i_ * 16 + lr;                      \
                af_[i_] = *(const bf16x8*)(A_ + row_ * 128 +                  \
                                           (cb_ ^ ((row_ & 7) << 4)));        \
            }                                                                 \
            _Pragma("unroll")                                                 \
            for (int j_ = 0; j_ < 4; ++j_) {                                  \
                const int row_ = wc * 64 + j_ * 16 + lr;                      \
                bf_[j_] = *(const bf16x8*)(B_ + row_ * 128 +                  \
                                           (cb_ ^ ((row_ & 7) << 4)));        \
            }                                                                 \
            _Pragma("unroll")                                                 \
            for (int i_ = 0; i_ < 4; ++i_)                                    \
                _Pragma("unroll")                                             \
                for (int j_ = 0; j_ < 4; ++j_)                                \
                    acc[i_][j_] = __builtin_amdgcn_mfma_f32_16x16x32_bf16(    \
                        af_[i_], bf_[j_], acc[i_][j_], 0, 0, 0);              \
        }                                                                     \
    } while (0)

    f32x4 acc[4][4] = {};
    GSTAGE(0);
#pragma unroll 1
    for (int tt = 0; tt < 4; tt += 2) {
        GADV();
        GSTAGE(1);
        SB(); asm volatile("s_waitcnt vmcnt(8)" ::: "memory"); SB();
        __builtin_amdgcn_s_barrier(); SB();
        GCOMPUTE(0);
        SB(); __builtin_amdgcn_s_barrier(); SB();

        if (tt == 0) {
            GADV();
            GSTAGE(0);
            SB(); asm volatile("s_waitcnt vmcnt(8)" ::: "memory"); SB();
        } else {
            SB(); asm volatile("s_waitcnt vmcnt(0)" ::: "memory"); SB();
        }
        __builtin_amdgcn_s_barrier(); SB();
        GCOMPUTE(1);
        SB(); __builtin_amdgcn_s_barrier(); SB();
    }
#undef GSTAGE
#undef GADV
#undef GCOMPUTE

#pragma unroll
    for (int i = 0; i < 4; ++i)
#pragma unroll
        for (int j = 0; j < 4; ++j)
#pragma unroll
            for (int r = 0; r < 4; ++r) {
                int row = rbase + i * 16 + lk * 4 + r;
                int col = cbase + j * 16 + lr;
                __bf16 v = (__bf16)acc[i][j][r];
                if (!trans) outp[(size_t)row * DIM + col] = v;
                else        outp[(size_t)col * ROWS + row] = v;
            }
}

// ================= PATH A =================
// sp_kernel: s-tile 256q x 128k, 512 thr / 8 waves (4q x 2k), wave 64q x 64k.
// BK=32 x 8 phases; staging 2x24KB aliased under Pt[256][136] (69632B LDS).
__global__ __launch_bounds__(512, 4) void sp_kernel(const __bf16* __restrict__ Qb,
                                                    const __bf16* __restrict__ Kb,
                                                    __bf16* __restrict__ P,
                                                    float* __restrict__ lsum) {
    __shared__ __bf16 smem[34816];   // 69632B: staging [2][12288] / Pt[256][136]
    const int t = threadIdx.x;
    const int w = t >> 6, l = t & 63;
    const int wq = w >> 1, wk = w & 1;       // 4 q-waves x 2 k-waves
    const int lr = l & 15, lk = l >> 4;
    const int b = blockIdx.z;
    const int kb0 = blockIdx.x * 128;
    const int qb0 = blockIdx.y * 256;
    const __bf16* Q = Qb + (size_t)b * SEQ * 256;
    const __bf16* K = Kb + (size_t)b * SEQ * 256;
    __bf16* Pb = P + (size_t)b * SEQ * SEQ;

    // staging: 24 chunks of 1KB (16 rows x 64B). chunks 0-15 = Q (256 rows),
    // 16-23 = K (128 rows). wave w loads chunks {i*8+w : i<3}. swizzle
    // slot^((row>>1)&3).
    const int lrow = l >> 2;       // row within 16-row chunk
    const int lslot = l & 3;       // 16B slot within 64B row
    const __bf16* src[3];
#pragma unroll
    for (int i = 0; i < 3; ++i) {
        const int chunk = i * 8 + w;
        if (chunk < 16) {
            const int qr = chunk * 16 + lrow;
            src[i] = Q + (size_t)(qb0 + qr) * 256 + ((lslot ^ ((qr >> 1) & 3)) * 8);
        } else {
            const int kr = (chunk - 16) * 16 + lrow;
            src[i] = K + (size_t)(kb0 + kr) * 256 + ((lslot ^ ((kr >> 1) & 3)) * 8);
        }
    }

#define SPSTAGE(bi) do {                                                      \
        _Pragma("unroll")                                                     \
        for (int i_ = 0; i_ < 3; ++i_) {                                      \
            const int chunk_ = i_ * 8 + w;                                    \
            __builtin_amdgcn_global_load_lds(                                 \
                (const unsigned int*)src[i_],                                 \
                (unsigned int*)&smem[(bi) * 12288 + chunk_ * 512], 16, 0, 0); \
        }                                                                     \
    } while (0)
#define SPADV() do { _Pragma("unroll") for (int x_ = 0; x_ < 3; ++x_) src[x_] += 32; } while (0)

#define SPCOMPUTE(bi) do {                                                    \
        const char* A_ = (const char*)smem + (bi) * 24576;                    \
        const char* B_ = A_ + 32768;   /* K at chunk 16 = 16KB into buf */    \
        bf16x8 af_[4], bf_[4];                                                \
        _Pragma("unroll")                                                     \
        for (int i_ = 0; i_ < 4; ++i_) {                                      \
            const int qr_ = wq * 64 + i_ * 16 + lr;                           \
            af_[i_] = *(const bf16x8*)(A_ + qr_ * 64 +                        \
                                       ((lk ^ ((qr_ >> 1) & 3)) * 16));       \
            const int kr_ = wk * 64 + i_ * 16 + lr;                           \
            bf_[i_] = *(const bf16x8*)(B_ + kr_ * 64 +                        \
                                       ((lk ^ ((kr_ >> 1) & 3)) * 16));       \
        }                                                                     \
        _Pragma("unroll")                                                     \
        for (int i_ = 0; i_ < 4; ++i_)                                        \
            _Pragma("unroll")                                                 \
            for (int j_ = 0; j_ < 4; ++j_)                                    \
                acc[i_][j_] = __builtin_amdgcn_mfma_f32_16x16x32_bf16(        \
                    af_[i_], bf_[j_], acc[i_][j_], 0, 0, 0);                  \
    } while (0)

    // NOTE: buf layout in bytes: buf bi at bi*24576; Q = bytes [0,16384),
    // K = bytes [16384, 24576). B_ above must be A_ + 16384.  (fixed below)
#undef SPCOMPUTE
#define SPCOMPUTE(bi) do {                                                    \
        const char* A_ = (const char*)smem + (bi) * 24576;                    \
        const char* B_ = A_ + 16384;                                          \
        bf16x8 af_[4], bf_[4];                                                \
        _Pragma("unroll")                                                     \
        for (int i_ = 0; i_ < 4; ++i_) {                                      \
            const int qr_ = wq * 64 + i_ * 16 + lr;                           \
            af_[i_] = *(const bf16x8*)(A_ + qr_ * 64 +                        \
                                       ((lk ^ ((qr_ >> 1) & 3)) * 16));       \
            const int kr_ = wk * 64 + i_ * 16 + lr;                           \
            bf_[i_] = *(const bf16x8*)(B_ + kr_ * 64 +                        \
                                       ((lk ^ ((kr_ >> 1) & 3)) * 16));       \
        }                                                                     \
        _Pragma("unroll")                                                     \
        for (int i_ = 0; i_ < 4; ++i_)                                        \
            _Pragma("unroll")                                                 \
            for (int j_ = 0; j_ < 4; ++j_)                                    \
                acc[i_][j_] = __builtin_amdgcn_mfma_f32_16x16x32_bf16(        \
                    af_[i_], bf_[j_], acc[i_][j_], 0, 0, 0);                  \
    } while (0)

    f32x4 acc[4][4] = {};
    SPSTAGE(0);
#pragma unroll 1
    for (int tt = 0; tt < 8; tt += 2) {
        SPADV();
        SPSTAGE(1);
        SB(); asm volatile("s_waitcnt vmcnt(3)" ::: "memory"); SB();
        __builtin_amdgcn_s_barrier(); SB();
        SPCOMPUTE(0);
        SB(); __builtin_amdgcn_s_barrier(); SB();

        if (tt < 6) {
            SPADV();
            SPSTAGE(0);
            SB(); asm volatile("s_waitcnt vmcnt(3)" ::: "memory"); SB();
        } else {
            SB(); asm volatile("s_waitcnt vmcnt(0)" ::: "memory"); SB();
        }
        __builtin_amdgcn_s_barrier(); SB();
        SPCOMPUTE(1);
        SB(); __builtin_amdgcn_s_barrier(); SB();
    }
#undef SPSTAGE
#undef SPADV
#undef SPCOMPUTE

    // exp epilogue into Pt[256][136] (aliases smem; staging consumed)
    __bf16* Pt = smem;
#pragma unroll
    for (int j = 0; j < 4; ++j) {
        float cs = 0.f;
#pragma unroll
        for (int i = 0; i < 4; ++i)
#pragma unroll
            for (int r = 0; r < 4; ++r) {
                float v = __expf(acc[i][j][r] * 0.0625f);
                cs += v;
                Pt[(wq * 64 + i * 16 + lk * 4 + r) * 136 + wk * 64 + j * 16 + lr] = (__bf16)v;
            }
        cs += __shfl_xor(cs, 16, 64);
        cs += __shfl_xor(cs, 32, 64);
        if (lk == 0)
            atomicAdd(&lsum[(size_t)b * SEQ + kb0 + wk * 64 + j * 16 + lr], cs);
    }
    __syncthreads();
    // coalesced store: 256 rows x 16 chunks(16B) = 4096 stores / 512 thr
#pragma unroll
    for (int it = 0; it < 8; ++it) {
        int n = it * 512 + t;
        int row = n >> 4;
        int ch = n & 15;
        *(bf16x8*)(Pb + (size_t)(qb0 + row) * SEQ + kb0 + ch * 8) =
            *(const bf16x8*)(&Pt[row * 136 + ch * 8]);
    }
}

// scale Vt rows by 1/l (vectorized x8): Vt[v][b*S+k] *= 1/l[b*S+k]
__global__ void scale_vt(__bf16* __restrict__ Vt,
                         const float* __restrict__ lsum, int n8) {
    int i = blockIdx.x * blockDim.x + threadIdx.x;
    if (i >= n8) return;
    int col8 = (i & (ROWS / 8 - 1)) * 8;
    bf16x8 d = *(const bf16x8*)(Vt + (size_t)i * 8);
#pragma unroll
    for (int j = 0; j < 8; ++j)
        d[j] = (__bf16)((float)d[j] / lsum[col8 + j]);
    *(bf16x8*)(Vt + (size_t)i * 8) = d;
}

// PV GEMM: out[q,v] = sum_k P[q,k] * Vt[v][b*S+k].  (P flat: [qglob][SEQ])
// Tile 128q x 128v, 512 thr = 8 waves (2q x 4v), wave-tile 64q x 32v.
// BK=64, 2x32KB dbuf, vmcnt(4), fenced. Grid 256 blocks 1D + XCD swizzle.
__global__ __launch_bounds__(512) void pv_gemm(const __bf16* __restrict__ P,
                                               const __bf16* __restrict__ Vt,
                                               float* __restrict__ out) {
    __shared__ __bf16 lds[32768];   // [2][16384]: A(P) 16KB | B(Vt) 16KB per buf
    const int t = threadIdx.x;
    const int w = t >> 6, l = t & 63;
    const int wq = w >> 2, wv = w & 3;       // 2q x 4v waves
    const int lr = l & 15, lk = l >> 4;

    const int fid = blockIdx.x;
    const int remap = (fid & 7) * 32 + (fid >> 3);
    const int vtile = remap >> 7;                // 0..1
    const int rowblk = remap & 127;              // 0..127
    const int row_blk = rowblk * 128;            // global q-row base
    const int b = rowblk >> 5;
    const int vbase = vtile * 128;
    const size_t bS = (size_t)b * SEQ;

    const int lrow = l >> 3;
    const int lslot = l & 7;
    const __bf16* src[4];
#pragma unroll
    for (int i = 0; i < 4; ++i) {
        const int chunk = i * 8 + w;             // 32 chunks over 8 waves
        if (chunk < 16) {
            const int arow = chunk * 8 + lrow;
            src[i] = P + (size_t)(row_blk + arow) * SEQ + ((lslot ^ (arow & 7)) * 8);
        } else {
            const int vrow = (chunk - 16) * 8 + lrow;
            src[i] = Vt + (size_t)(vbase + vrow) * ROWS + bS + ((lslot ^ (vrow & 7)) * 8);
        }
    }

#define STAGE(bi) do {                                                        \
        _Pragma("unroll")                                                     \
        for (int i_ = 0; i_ < 4; ++i_) {                                      \
            const int chunk_ = i_ * 8 + w;                                    \
            __builtin_amdgcn_global_load_lds(                                 \
                (const unsigned int*)src[i_],                                 \
                (unsigned int*)&lds[(bi) * 16384 + chunk_ * 512], 16, 0, 0);  \
        }                                                                     \
    } while (0)

#define ADV() do { _Pragma("unroll") for (int i_ = 0; i_ < 4; ++i_) src[i_] += 64; } while (0)

#define COMPUTE(bi) do {                                                      \
        const char* A_ = (const char*)lds + (bi) * 32768;                     \
        const char* B_ = A_ + 16384;                                          \
        _Pragma("unroll")                                                     \
        for (int ks_ = 0; ks_ < 2; ++ks_) {                                   \
            bf16x8 af_[4], bf_[2];                                            \
            const int cb_ = ks_ * 64 + lk * 16;                               \
            _Pragma("unroll")                                                 \
            for (int i_ = 0; i_ < 4; ++i_) {                                  \
                const int row_ = wq * 64 + i_ * 16 + lr;                      \
                af_[i_] = *(const bf16x8*)(A_ + row_ * 128 +                  \
                                           (cb_ ^ ((row_ & 7) << 4)));        \
            }                                                                 \
            _Pragma("unroll")                                                 \
            for (int j_ = 0; j_ < 2; ++j_) {                                  \
                const int row_ = wv * 32 + j_ * 16 + lr;                      \
                bf_[j_] = *(const bf16x8*)(B_ + row_ * 128 +                  \
                                           (cb_ ^ ((row_ & 7) << 4)));        \
            }                                                                 \
            _Pragma("unroll")                                                 \
            for (int i_ = 0; i_ < 4; ++i_)                                    \
                _Pragma("unroll")                                             \
                for (int j_ = 0; j_ < 2; ++j_)                                \
                    acc[i_][j_] = __builtin_amdgcn_mfma_f32_16x16x32_bf16(    \
                        af_[i_], bf_[j_], acc[i_][j_], 0, 0, 0);              \
        }                                                                     \
    } while (0)

    f32x4 acc[4][2] = {};
    STAGE(0);
#pragma unroll 1
    for (int tt = 0; tt < 64; tt += 2) {
        if (tt < 63) ADV();
        STAGE(1);
        SB(); asm volatile("s_waitcnt vmcnt(4)" ::: "memory"); SB();
        __builtin_amdgcn_s_barrier(); SB();
        COMPUTE(0);
        SB(); __builtin_amdgcn_s_barrier(); SB();

        if (tt + 1 < 63) ADV();
        STAGE(0);
        SB(); asm volatile("s_waitcnt vmcnt(4)" ::: "memory"); SB();
        __builtin_amdgcn_s_barrier(); SB();
        COMPUTE(1);
        SB(); __builtin_amdgcn_s_barrier(); SB();
    }
#undef STAGE
#undef ADV
#undef COMPUTE

#pragma unroll
    for (int i = 0; i < 4; ++i)
#pragma unroll
        for (int j = 0; j < 2; ++j)
#pragma unroll
            for (int r = 0; r < 4; ++r) {
                const int row = row_blk + wq * 64 + i * 16 + lk * 4 + r;
                const int col = vbase + wv * 32 + j * 16 + lr;
                out[(size_t)row * 256 + col] = acc[i][j][r];
            }
}

// ================= PATH B (fallback) =================
__global__ __launch_bounds__(256) void colsumexp(const __bf16* __restrict__ Qb,
                                                 const __bf16* __restrict__ Kb,
                                                 float* __restrict__ lsum) {
    const int l = threadIdx.x & 63;
    const int w = threadIdx.x >> 6;
    const int wr = w >> 1, wc = w & 1;
    const int lr = l & 15, lk = l >> 4;
    const int b = blockIdx.z;
    const int cbase = blockIdx.x * 128 + wc * 64;
    const __bf16* Q = Qb + (size_t)b * SEQ * 256;
    const __bf16* K = Kb + (size_t)b * SEQ * 256;

    float csum[4] = {0.f, 0.f, 0.f, 0.f};
    for (int qi = 0; qi < 16; ++qi) {
        const int rbase = blockIdx.y * 2048 + qi * 128 + wr * 64;
        f32x4 acc[4][4] = {};
#pragma unroll
        for (int d0 = 0; d0 < 256; d0 += 32) {
            bf16x8 a[4], bb[4];
#pragma unroll
            for (int i = 0; i < 4; ++i)
                a[i] = *(const bf16x8*)(Q + (size_t)(rbase + i * 16 + lr) * 256 + d0 + lk * 8);
#pragma unroll
            for (int j = 0; j < 4; ++j)
                bb[j] = *(const bf16x8*)(K + (size_t)(cbase + j * 16 + lr) * 256 + d0 + lk * 8);
#pragma unroll
            for (int i = 0; i < 4; ++i)
#pragma unroll
                for (int j = 0; j < 4; ++j)
                    acc[i][j] = __builtin_amdgcn_mfma_f32_16x16x32_bf16(a[i], bb[j], acc[i][j], 0, 0, 0);
        }
#pragma unroll
        for (int j = 0; j < 4; ++j) {
            float s = 0.f;
#pragma unroll
            for (int i = 0; i < 4; ++i)
#pragma unroll
                for (int r = 0; r < 4; ++r)
                    s += __expf(acc[i][j][r] * 0.0625f);
            csum[j] += s;
        }
    }
#pragma unroll
    for (int j = 0; j < 4; ++j) {
        float s = csum[j];
        s += __shfl_xor(s, 16, 64);
        s += __shfl_xor(s, 32, 64);
        if (lk == 0)
            atomicAdd(&lsum[(size_t)b * SEQ + cbase + j * 16 + lr], s);
    }
}

__global__ __launch_bounds__(256) void pv_kernel(const __bf16* __restrict__ Qb,
                                                 const __bf16* __restrict__ Kb,
                                                 const __bf16* __restrict__ Vt,
                                                 float* __restrict__ out) {
    __shared__ __bf16 Pl[128][72];
    const int l = threadIdx.x & 63;
    const int w = threadIdx.x >> 6;
    const int wr = w >> 1, wc = w & 1;
    const int lr = l & 15, lk = l >> 4;
    const int b = blockIdx.z;
    const int qbase = blockIdx.x * 128;
    const int vbase = blockIdx.y * 128;
    const __bf16* Q = Qb + (size_t)b * SEQ * 256;
    const __bf16* K = Kb + (size_t)b * SEQ * 256;
    const __bf16* V = Vt + (size_t)b * SEQ;

    f32x4 oacc[4][4] = {};
    for (int k0 = 0; k0 < SEQ; k0 += 64) {
        f32x4 sacc[4][2] = {};
#pragma unroll
        for (int d0 = 0; d0 < 256; d0 += 32) {
            bf16x8 a[4], bb[2];
#pragma unroll
            for (int i = 0; i < 4; ++i)
                a[i] = *(const bf16x8*)(Q + (size_t)(qbase + wr * 64 + i * 16 + lr) * 256 + d0 + lk * 8);
#pragma unroll
            for (int j = 0; j < 2; ++j)
                bb[j] = *(const bf16x8*)(K + (size_t)(k0 + wc * 32 + j * 16 + lr) * 256 + d0 + lk * 8);
#pragma unroll
            for (int i = 0; i < 4; ++i)
#pragma unroll
                for (int j = 0; j < 2; ++j)
                    sacc[i][j] = __builtin_amdgcn_mfma_f32_16x16x32_bf16(a[i], bb[j], sacc[i][j], 0, 0, 0);
        }
#pragma unroll
        for (int i = 0; i < 4; ++i)
#pragma unroll
            for (int j = 0; j < 2; ++j)
#pragma unroll
                for (int r = 0; r < 4; ++r)
                    Pl[wr * 64 + i * 16 + lk * 4 + r][wc * 32 + j * 16 + lr] =
                        (__bf16)__expf(sacc[i][j][r] * 0.0625f);
        __syncthreads();
#pragma unroll
        for (int ks = 0; ks < 2; ++ks) {
            bf16x8 a[4], bb[4];
#pragma unroll
            for (int i = 0; i < 4; ++i)
                a[i] = *(const bf16x8*)(&Pl[wr * 64 + i * 16 + lr][ks * 32 + lk * 8]);
#pragma unroll
            for (int j = 0; j < 4; ++j)
                bb[j] = *(const bf16x8*)(V + (size_t)(vbase + wc * 64 + j * 16 + lr) * ROWS + k0 + ks * 32 + lk * 8);
#pragma unroll
            for (int i = 0; i < 4; ++i)
#pragma unroll
                for (int j = 0; j < 4; ++j)
                    oacc[i][j] = __builtin_amdgcn_mfma_f32_16x16x32_bf16(a[i], bb[j], oacc[i][j], 0, 0, 0);
        }
        __syncthreads();
    }
    float* O = out + (size_t)b * SEQ * 256;
#pragma unroll
    for (int i = 0; i < 4; ++i)
#pragma unroll
        for (int j = 0; j < 4; ++j)
#pragma unroll
            for (int r = 0; r < 4; ++r) {
                int row = qbase + wr * 64 + i * 16 + lk * 4 + r;
                int col = vbase + wc * 64 + j * 16 + lr;
                O[(size_t)row * 256 + col] = oacc[i][j][r];
            }
}

extern "C" void kernel_launch(void* const* d_in, const int* in_sizes, int n_in,
                              void* d_out, int out_size, void* d_ws, size_t ws_size,
                              hipStream_t stream) {
    const float* x  = (const float*)d_in[0];
    const float* wq = (const float*)d_in[1];
    const float* wk = (const float*)d_in[2];
    const float* wv = (const float*)d_in[3];
    float* out = (float*)d_out;

    char* ws = (char*)d_ws;
    __bf16* Xb  = (__bf16*)(ws + 0);
    __bf16* Qb  = (__bf16*)(ws + 8388608);
    __bf16* Kb  = (__bf16*)(ws + 16777216);
    __bf16* Vt  = (__bf16*)(ws + 25165824);
    __bf16* Wqb = (__bf16*)(ws + 33554432);
    __bf16* Wkb = (__bf16*)(ws + 33685504);
    __bf16* Wvb = (__bf16*)(ws + 33816576);
    float*  lsum = (float*)(ws + 33947648);
    __bf16* Pbuf = (__bf16*)(ws + 34013184);
    const size_t need_A = 34013184 + (size_t)BATCH * SEQ * SEQ * 2;   // ~168 MB

    const int n_x = ROWS * DIM;      // 4194304

    cast_v8<<<(n_x / 8 + 255) / 256, 256, 0, stream>>>(x, Xb, n_x / 8);
    cast_w3<<<(3 * 8192 + 255) / 256, 256, 0, stream>>>(wq, wk, wv, Wqb, Wkb, Wvb);

    dim3 gg(ROWS / 128, DIM / 128, 3);   // (128, 2, 3)
    gemm_qkv<<<gg, 256, 0, stream>>>(Xb, Wqb, Wkb, Wvb, Qb, Kb, Vt);

    hipMemsetAsync(lsum, 0, (size_t)BATCH * SEQ * sizeof(float), stream);

    if (ws_size >= need_A) {
        dim3 gs(SEQ / 128, SEQ / 256, BATCH);   // (32, 16, 4) = 2048 blocks
        sp_kernel<<<gs, 512, 0, stream>>>(Qb, Kb, Pbuf, lsum);
        scale_vt<<<(n_x / 8 + 255) / 256, 256, 0, stream>>>(Vt, lsum, n_x / 8);
        pv_gemm<<<256, 512, 0, stream>>>(Pbuf, Vt, out);
    } else {
        dim3 gs(SEQ / 128, 2, BATCH);
        colsumexp<<<gs, 256, 0, stream>>>(Qb, Kb, lsum);
        scale_vt<<<(n_x / 8 + 255) / 256, 256, 0, stream>>>(Vt, lsum, n_x / 8);
        dim3 gp(SEQ / 128, DIM / 128, BATCH);
        pv_kernel<<<gp, 256, 0, stream>>>(Qb, Kb, Vt, out);
    }
}

// Round 20
// 137.107 us; speedup vs baseline: 1.0834x; 1.0208x over previous
//
#include <hip/hip_runtime.h>
#include <hip/hip_bf16.h>

// Self-attention with softmax over the QUERY axis (dim=1):
//   Q=XWq^T K=XWk^T V=XWv^T ; s = QK^T/16 ; attn[:,q,k] = exp(s)/sum_q exp(s)
//   out = attn @ V
// B=4, S=4096, D=Q_DIM=256.
//
// Best-known configuration (R16, 137.3 us):
//   gemm_qkv: staged (global_load_lds, BK=64, vmcnt(8), fenced).
//   sp_kernel: staged QK^T, BK=32 x 8 phases, 34.8KB LDS -> 4 blocks/CU.
//   pv_gemm: 128q x 128v tile, 512 thr = 8 waves (2q x 4v), BK=64, 2x32KB dbuf,
//     vmcnt(4), fenced; grid 256 blocks 1D + bijective XCD swizzle.
// Path B: flash-style fallback.

#define BATCH 4
#define SEQ 4096
#define DIM 256
#define ROWS (BATCH * SEQ)   // 16384

typedef __bf16 bf16x8 __attribute__((ext_vector_type(8)));
typedef float f32x4 __attribute__((ext_vector_type(4)));

#define SB() __builtin_amdgcn_sched_barrier(0)

// ---------------- vectorized cast f32 -> bf16 (n multiple of 8) ----------------
__global__ void cast_v8(const float* __restrict__ in,
                        __bf16* __restrict__ out, int n8) {
    int i = blockIdx.x * blockDim.x + threadIdx.x;
    if (i >= n8) return;
    const float4 f0 = *(const float4*)(in + (size_t)i * 8);
    const float4 f1 = *(const float4*)(in + (size_t)i * 8 + 4);
    bf16x8 o;
    o[0] = (__bf16)f0.x; o[1] = (__bf16)f0.y; o[2] = (__bf16)f0.z; o[3] = (__bf16)f0.w;
    o[4] = (__bf16)f1.x; o[5] = (__bf16)f1.y; o[6] = (__bf16)f1.z; o[7] = (__bf16)f1.w;
    *(bf16x8*)(out + (size_t)i * 8) = o;
}

// weights: 3 arrays of 65536 cast in one launch
__global__ void cast_w3(const float* __restrict__ w0, const float* __restrict__ w1,
                        const float* __restrict__ w2, __bf16* __restrict__ o0,
                        __bf16* __restrict__ o1, __bf16* __restrict__ o2) {
    int t = blockIdx.x * blockDim.x + threadIdx.x;   // 3 * 8192
    int arr = t >> 13;
    int i = (t & 8191);
    const float* in = arr == 0 ? w0 : arr == 1 ? w1 : w2;
    __bf16* out = arr == 0 ? o0 : arr == 1 ? o1 : o2;
    const float4 f0 = *(const float4*)(in + (size_t)i * 8);
    const float4 f1 = *(const float4*)(in + (size_t)i * 8 + 4);
    bf16x8 o;
    o[0] = (__bf16)f0.x; o[1] = (__bf16)f0.y; o[2] = (__bf16)f0.z; o[3] = (__bf16)f0.w;
    o[4] = (__bf16)f1.x; o[5] = (__bf16)f1.y; o[6] = (__bf16)f1.z; o[7] = (__bf16)f1.w;
    *(bf16x8*)(out + (size_t)i * 8) = o;
}

// ------- QKV GEMM (staged): z=0 Q, z=1 K, z=2 V(transposed store). -------
__global__ __launch_bounds__(256) void gemm_qkv(const __bf16* __restrict__ X,
                                                const __bf16* __restrict__ Wq,
                                                const __bf16* __restrict__ Wk,
                                                const __bf16* __restrict__ Wv,
                                                __bf16* __restrict__ Qo,
                                                __bf16* __restrict__ Ko,
                                                __bf16* __restrict__ Vo) {
    __shared__ __bf16 smem[32768];   // [2][16384]: X 16KB | W 16KB per buf
    const int z = blockIdx.z;
    const __bf16* Wz = z == 0 ? Wq : z == 1 ? Wk : Wv;
    __bf16* outp = z == 0 ? Qo : z == 1 ? Ko : Vo;
    const int trans = (z == 2);

    const int t = threadIdx.x;
    const int w = t >> 6, l = t & 63;
    const int wr = w >> 1, wc = w & 1;
    const int lr = l & 15, lk = l >> 4;
    const int rb0 = blockIdx.x * 128;
    const int cb0 = blockIdx.y * 128;
    const int rbase = rb0 + wr * 64;
    const int cbase = cb0 + wc * 64;

    const int lrow = l >> 3;
    const int lslot = l & 7;
    const __bf16* src[8];
#pragma unroll
    for (int i = 0; i < 8; ++i) {
        const int chunk = i * 4 + w;
        if (chunk < 16) {
            const int xr = chunk * 8 + lrow;
            src[i] = X + (size_t)(rb0 + xr) * 256 + ((lslot ^ (xr & 7)) * 8);
        } else {
            const int wrr = (chunk - 16) * 8 + lrow;
            src[i] = Wz + (size_t)(cb0 + wrr) * 256 + ((lslot ^ (wrr & 7)) * 8);
        }
    }

#define GSTAGE(bi) do {                                                       \
        _Pragma("unroll")                                                     \
        for (int i_ = 0; i_ < 8; ++i_) {                                      \
            const int chunk_ = i_ * 4 + w;                                    \
            __builtin_amdgcn_global_load_lds(                                 \
                (const unsigned int*)src[i_],                                 \
                (unsigned int*)&smem[(bi) * 16384 + chunk_ * 512], 16, 0, 0); \
        }                                                                     \
    } while (0)
#define GADV() do { _Pragma("unroll") for (int x_ = 0; x_ < 8; ++x_) src[x_] += 64; } while (0)

#define GCOMPUTE(bi) do {                                                     \
        const char* A_ = (const char*)smem + (bi) * 32768;                    \
        const char* B_ = A_ + 16384;                                          \
        _Pragma("unroll")                                                     \
        for (int ks_ = 0; ks_ < 2; ++ks_) {                                   \
            bf16x8 af_[4], bf_[4];                                            \
            const int cb_ = ks_ * 64 + lk * 16;                               \
            _Pragma("unroll")                                                 \
            for (int i_ = 0; i_ < 4; ++i_) {                                  \
                const int row_ = wr * 64 + i_ * 16 + lr;                      \
                af_[i_] = *(const bf16x8*)(A_ + row_ * 128 +                  \
                                           (cb_ ^ ((row_ & 7) << 4)));        \
            }                                                                 \
            _Pragma("unroll")                                                 \
            for (int j_ = 0; j_ < 4; ++j_) {                                  \
                const int row_ = wc * 64 + j_ * 16 + lr;                      \
                bf_[j_] = *(const bf16x8*)(B_ + row_ * 128 +                  \
                                           (cb_ ^ ((row_ & 7) << 4)));        \
            }                                                                 \
            _Pragma("unroll")                                                 \
            for (int i_ = 0; i_ < 4; ++i_)                                    \
                _Pragma("unroll")                                             \
                for (int j_ = 0; j_ < 4; ++j_)                                \
                    acc[i_][j_] = __builtin_amdgcn_mfma_f32_16x16x32_bf16(    \
                        af_[i_], bf_[j_], acc[i_][j_], 0, 0, 0);              \
        }                                                                     \
    } while (0)

    f32x4 acc[4][4] = {};
    GSTAGE(0);
#pragma unroll 1
    for (int tt = 0; tt < 4; tt += 2) {
        GADV();
        GSTAGE(1);
        SB(); asm volatile("s_waitcnt vmcnt(8)" ::: "memory"); SB();
        __builtin_amdgcn_s_barrier(); SB();
        GCOMPUTE(0);
        SB(); __builtin_amdgcn_s_barrier(); SB();

        if (tt == 0) {
            GADV();
            GSTAGE(0);
            SB(); asm volatile("s_waitcnt vmcnt(8)" ::: "memory"); SB();
        } else {
            SB(); asm volatile("s_waitcnt vmcnt(0)" ::: "memory"); SB();
        }
        __builtin_amdgcn_s_barrier(); SB();
        GCOMPUTE(1);
        SB(); __builtin_amdgcn_s_barrier(); SB();
    }
#undef GSTAGE
#undef GADV
#undef GCOMPUTE

#pragma unroll
    for (int i = 0; i < 4; ++i)
#pragma unroll
        for (int j = 0; j < 4; ++j)
#pragma unroll
            for (int r = 0; r < 4; ++r) {
                int row = rbase + i * 16 + lk * 4 + r;
                int col = cbase + j * 16 + lr;
                __bf16 v = (__bf16)acc[i][j][r];
                if (!trans) outp[(size_t)row * DIM + col] = v;
                else        outp[(size_t)col * ROWS + row] = v;
            }
}

// ================= PATH A =================
// sp_kernel: s-tile 128q x 128k staged GEMM. BK=32 x 8 phases; 34816B LDS.
__global__ __launch_bounds__(256) void sp_kernel(const __bf16* __restrict__ Qb,
                                                 const __bf16* __restrict__ Kb,
                                                 __bf16* __restrict__ P,
                                                 float* __restrict__ lsum) {
    __shared__ __bf16 smem[17408];   // 34816B: staging [2][8192] / Pt[128][136]
    const int t = threadIdx.x;
    const int w = t >> 6, l = t & 63;
    const int wq = w >> 1, wk = w & 1;
    const int lr = l & 15, lk = l >> 4;
    const int b = blockIdx.z;
    const int kb0 = blockIdx.x * 128;
    const int qb0 = blockIdx.y * 128;
    const __bf16* Q = Qb + (size_t)b * SEQ * 256;
    const __bf16* K = Kb + (size_t)b * SEQ * 256;
    __bf16* Pb = P + (size_t)b * SEQ * SEQ;

    const int lrow = l >> 2;       // row within 16-row chunk
    const int lslot = l & 3;       // 16B slot within 64B row
    const __bf16* src[4];
#pragma unroll
    for (int i = 0; i < 4; ++i) {
        const int chunk = i * 4 + w;
        if (chunk < 8) {
            const int qr = chunk * 16 + lrow;
            src[i] = Q + (size_t)(qb0 + qr) * 256 + ((lslot ^ ((qr >> 1) & 3)) * 8);
        } else {
            const int kr = (chunk - 8) * 16 + lrow;
            src[i] = K + (size_t)(kb0 + kr) * 256 + ((lslot ^ ((kr >> 1) & 3)) * 8);
        }
    }

#define SPSTAGE(bi) do {                                                      \
        _Pragma("unroll")                                                     \
        for (int i_ = 0; i_ < 4; ++i_) {                                      \
            const int chunk_ = i_ * 4 + w;                                    \
            __builtin_amdgcn_global_load_lds(                                 \
                (const unsigned int*)src[i_],                                 \
                (unsigned int*)&smem[(bi) * 8192 + chunk_ * 512], 16, 0, 0);  \
        }                                                                     \
    } while (0)
#define SPADV() do { _Pragma("unroll") for (int x_ = 0; x_ < 4; ++x_) src[x_] += 32; } while (0)

#define SPCOMPUTE(bi) do {                                                    \
        const char* A_ = (const char*)smem + (bi) * 16384;                    \
        const char* B_ = A_ + 8192;                                           \
        bf16x8 af_[4], bf_[4];                                                \
        _Pragma("unroll")                                                     \
        for (int i_ = 0; i_ < 4; ++i_) {                                      \
            const int qr_ = wq * 64 + i_ * 16 + lr;                           \
            af_[i_] = *(const bf16x8*)(A_ + qr_ * 64 +                        \
                                       ((lk ^ ((qr_ >> 1) & 3)) * 16));       \
            const int kr_ = wk * 64 + i_ * 16 + lr;                           \
            bf_[i_] = *(const bf16x8*)(B_ + kr_ * 64 +                        \
                                       ((lk ^ ((kr_ >> 1) & 3)) * 16));       \
        }                                                                     \
        _Pragma("unroll")                                                     \
        for (int i_ = 0; i_ < 4; ++i_)                                        \
            _Pragma("unroll")                                                 \
            for (int j_ = 0; j_ < 4; ++j_)                                    \
                acc[i_][j_] = __builtin_amdgcn_mfma_f32_16x16x32_bf16(        \
                    af_[i_], bf_[j_], acc[i_][j_], 0, 0, 0);                  \
    } while (0)

    f32x4 acc[4][4] = {};
    SPSTAGE(0);
#pragma unroll 1
    for (int tt = 0; tt < 8; tt += 2) {
        SPADV();
        SPSTAGE(1);
        SB(); asm volatile("s_waitcnt vmcnt(4)" ::: "memory"); SB();
        __builtin_amdgcn_s_barrier(); SB();
        SPCOMPUTE(0);
        SB(); __builtin_amdgcn_s_barrier(); SB();

        if (tt < 6) {
            SPADV();
            SPSTAGE(0);
            SB(); asm volatile("s_waitcnt vmcnt(4)" ::: "memory"); SB();
        } else {
            SB(); asm volatile("s_waitcnt vmcnt(0)" ::: "memory"); SB();
        }
        __builtin_amdgcn_s_barrier(); SB();
        SPCOMPUTE(1);
        SB(); __builtin_amdgcn_s_barrier(); SB();
    }
#undef SPSTAGE
#undef SPADV
#undef SPCOMPUTE

    __bf16* Pt = smem;   // [128][136]
#pragma unroll
    for (int j = 0; j < 4; ++j) {
        float cs = 0.f;
#pragma unroll
        for (int i = 0; i < 4; ++i)
#pragma unroll
            for (int r = 0; r < 4; ++r) {
                float v = __expf(acc[i][j][r] * 0.0625f);
                cs += v;
                Pt[(wq * 64 + i * 16 + lk * 4 + r) * 136 + wk * 64 + j * 16 + lr] = (__bf16)v;
            }
        cs += __shfl_xor(cs, 16, 64);
        cs += __shfl_xor(cs, 32, 64);
        if (lk == 0)
            atomicAdd(&lsum[(size_t)b * SEQ + kb0 + wk * 64 + j * 16 + lr], cs);
    }
    __syncthreads();
#pragma unroll
    for (int it = 0; it < 8; ++it) {
        int n = it * 256 + t;
        int row = n >> 4;
        int ch = n & 15;
        *(bf16x8*)(Pb + (size_t)(qb0 + row) * SEQ + kb0 + ch * 8) =
            *(const bf16x8*)(&Pt[row * 136 + ch * 8]);
    }
}

// scale Vt rows by 1/l (vectorized x8): Vt[v][b*S+k] *= 1/l[b*S+k]
__global__ void scale_vt(__bf16* __restrict__ Vt,
                         const float* __restrict__ lsum, int n8) {
    int i = blockIdx.x * blockDim.x + threadIdx.x;
    if (i >= n8) return;
    int col8 = (i & (ROWS / 8 - 1)) * 8;
    bf16x8 d = *(const bf16x8*)(Vt + (size_t)i * 8);
#pragma unroll
    for (int j = 0; j < 8; ++j)
        d[j] = (__bf16)((float)d[j] / lsum[col8 + j]);
    *(bf16x8*)(Vt + (size_t)i * 8) = d;
}

// PV GEMM: out[q,v] = sum_k P[q,k] * Vt[v][b*S+k].  (P flat: [qglob][SEQ])
// Tile 128q x 128v, 512 thr = 8 waves (2q x 4v), wave-tile 64q x 32v.
// BK=64, 2x32KB dbuf, vmcnt(4), fenced. Grid 256 blocks 1D + XCD swizzle.
__global__ __launch_bounds__(512) void pv_gemm(const __bf16* __restrict__ P,
                                               const __bf16* __restrict__ Vt,
                                               float* __restrict__ out) {
    __shared__ __bf16 lds[32768];   // [2][16384]: A(P) 16KB | B(Vt) 16KB per buf
    const int t = threadIdx.x;
    const int w = t >> 6, l = t & 63;
    const int wq = w >> 2, wv = w & 3;       // 2q x 4v waves
    const int lr = l & 15, lk = l >> 4;

    // bijective XCD swizzle over 256 blocks: remap=(fid%8)*32+fid/8
    const int fid = blockIdx.x;
    const int remap = (fid & 7) * 32 + (fid >> 3);
    const int vtile = remap >> 7;                // 0..1
    const int rowblk = remap & 127;              // 0..127
    const int row_blk = rowblk * 128;            // global q-row base
    const int b = rowblk >> 5;
    const int vbase = vtile * 128;
    const size_t bS = (size_t)b * SEQ;

    const int lrow = l >> 3;
    const int lslot = l & 7;
    const __bf16* src[4];
#pragma unroll
    for (int i = 0; i < 4; ++i) {
        const int chunk = i * 8 + w;             // 32 chunks over 8 waves
        if (chunk < 16) {          // A: P rows 0..127
            const int arow = chunk * 8 + lrow;
            src[i] = P + (size_t)(row_blk + arow) * SEQ + ((lslot ^ (arow & 7)) * 8);
        } else {                   // B: Vt rows 0..127
            const int vrow = (chunk - 16) * 8 + lrow;
            src[i] = Vt + (size_t)(vbase + vrow) * ROWS + bS + ((lslot ^ (vrow & 7)) * 8);
        }
    }

#define STAGE(bi) do {                                                        \
        _Pragma("unroll")                                                     \
        for (int i_ = 0; i_ < 4; ++i_) {                                      \
            const int chunk_ = i_ * 8 + w;                                    \
            __builtin_amdgcn_global_load_lds(                                 \
                (const unsigned int*)src[i_],                                 \
                (unsigned int*)&lds[(bi) * 16384 + chunk_ * 512], 16, 0, 0);  \
        }                                                                     \
    } while (0)

#define ADV() do { _Pragma("unroll") for (int i_ = 0; i_ < 4; ++i_) src[i_] += 64; } while (0)

#define COMPUTE(bi) do {                                                      \
        const char* A_ = (const char*)lds + (bi) * 32768;                     \
        const char* B_ = A_ + 16384;                                          \
        _Pragma("unroll")                                                     \
        for (int ks_ = 0; ks_ < 2; ++ks_) {                                   \
            bf16x8 af_[4], bf_[2];                                            \
            const int cb_ = ks_ * 64 + lk * 16;                               \
            _Pragma("unroll")                                                 \
            for (int i_ = 0; i_ < 4; ++i_) {                                  \
                const int row_ = wq * 64 + i_ * 16 + lr;                      \
                af_[i_] = *(const bf16x8*)(A_ + row_ * 128 +                  \
                                           (cb_ ^ ((row_ & 7) << 4)));        \
            }                                                                 \
            _Pragma("unroll")                                                 \
            for (int j_ = 0; j_ < 2; ++j_) {                                  \
                const int row_ = wv * 32 + j_ * 16 + lr;                      \
                bf_[j_] = *(const bf16x8*)(B_ + row_ * 128 +                  \
                                           (cb_ ^ ((row_ & 7) << 4)));        \
            }                                                                 \
            _Pragma("unroll")                                                 \
            for (int i_ = 0; i_ < 4; ++i_)                                    \
                _Pragma("unroll")                                             \
                for (int j_ = 0; j_ < 2; ++j_)                                \
                    acc[i_][j_] = __builtin_amdgcn_mfma_f32_16x16x32_bf16(    \
                        af_[i_], bf_[j_], acc[i_][j_], 0, 0, 0);              \
        }                                                                     \
    } while (0)

    f32x4 acc[4][2] = {};
    STAGE(0);
#pragma unroll 1
    for (int tt = 0; tt < 64; tt += 2) {
        if (tt < 63) ADV();
        STAGE(1);
        SB(); asm volatile("s_waitcnt vmcnt(4)" ::: "memory"); SB();
        __builtin_amdgcn_s_barrier(); SB();
        COMPUTE(0);
        SB(); __builtin_amdgcn_s_barrier(); SB();

        if (tt + 1 < 63) ADV();
        STAGE(0);
        SB(); asm volatile("s_waitcnt vmcnt(4)" ::: "memory"); SB();
        __builtin_amdgcn_s_barrier(); SB();
        COMPUTE(1);
        SB(); __builtin_amdgcn_s_barrier(); SB();
    }
#undef STAGE
#undef ADV
#undef COMPUTE

#pragma unroll
    for (int i = 0; i < 4; ++i)
#pragma unroll
        for (int j = 0; j < 2; ++j)
#pragma unroll
            for (int r = 0; r < 4; ++r) {
                const int row = row_blk + wq * 64 + i * 16 + lk * 4 + r;
                const int col = vbase + wv * 32 + j * 16 + lr;
                out[(size_t)row * 256 + col] = acc[i][j][r];
            }
}

// ================= PATH B (fallback) =================
__global__ __launch_bounds__(256) void colsumexp(const __bf16* __restrict__ Qb,
                                                 const __bf16* __restrict__ Kb,
                                                 float* __restrict__ lsum) {
    const int l = threadIdx.x & 63;
    const int w = threadIdx.x >> 6;
    const int wr = w >> 1, wc = w & 1;
    const int lr = l & 15, lk = l >> 4;
    const int b = blockIdx.z;
    const int cbase = blockIdx.x * 128 + wc * 64;
    const __bf16* Q = Qb + (size_t)b * SEQ * 256;
    const __bf16* K = Kb + (size_t)b * SEQ * 256;

    float csum[4] = {0.f, 0.f, 0.f, 0.f};
    for (int qi = 0; qi < 16; ++qi) {
        const int rbase = blockIdx.y * 2048 + qi * 128 + wr * 64;
        f32x4 acc[4][4] = {};
#pragma unroll
        for (int d0 = 0; d0 < 256; d0 += 32) {
            bf16x8 a[4], bb[4];
#pragma unroll
            for (int i = 0; i < 4; ++i)
                a[i] = *(const bf16x8*)(Q + (size_t)(rbase + i * 16 + lr) * 256 + d0 + lk * 8);
#pragma unroll
            for (int j = 0; j < 4; ++j)
                bb[j] = *(const bf16x8*)(K + (size_t)(cbase + j * 16 + lr) * 256 + d0 + lk * 8);
#pragma unroll
            for (int i = 0; i < 4; ++i)
#pragma unroll
                for (int j = 0; j < 4; ++j)
                    acc[i][j] = __builtin_amdgcn_mfma_f32_16x16x32_bf16(a[i], bb[j], acc[i][j], 0, 0, 0);
        }
#pragma unroll
        for (int j = 0; j < 4; ++j) {
            float s = 0.f;
#pragma unroll
            for (int i = 0; i < 4; ++i)
#pragma unroll
                for (int r = 0; r < 4; ++r)
                    s += __expf(acc[i][j][r] * 0.0625f);
            csum[j] += s;
        }
    }
#pragma unroll
    for (int j = 0; j < 4; ++j) {
        float s = csum[j];
        s += __shfl_xor(s, 16, 64);
        s += __shfl_xor(s, 32, 64);
        if (lk == 0)
            atomicAdd(&lsum[(size_t)b * SEQ + cbase + j * 16 + lr], s);
    }
}

__global__ __launch_bounds__(256) void pv_kernel(const __bf16* __restrict__ Qb,
                                                 const __bf16* __restrict__ Kb,
                                                 const __bf16* __restrict__ Vt,
                                                 float* __restrict__ out) {
    __shared__ __bf16 Pl[128][72];
    const int l = threadIdx.x & 63;
    const int w = threadIdx.x >> 6;
    const int wr = w >> 1, wc = w & 1;
    const int lr = l & 15, lk = l >> 4;
    const int b = blockIdx.z;
    const int qbase = blockIdx.x * 128;
    const int vbase = blockIdx.y * 128;
    const __bf16* Q = Qb + (size_t)b * SEQ * 256;
    const __bf16* K = Kb + (size_t)b * SEQ * 256;
    const __bf16* V = Vt + (size_t)b * SEQ;

    f32x4 oacc[4][4] = {};
    for (int k0 = 0; k0 < SEQ; k0 += 64) {
        f32x4 sacc[4][2] = {};
#pragma unroll
        for (int d0 = 0; d0 < 256; d0 += 32) {
            bf16x8 a[4], bb[2];
#pragma unroll
            for (int i = 0; i < 4; ++i)
                a[i] = *(const bf16x8*)(Q + (size_t)(qbase + wr * 64 + i * 16 + lr) * 256 + d0 + lk * 8);
#pragma unroll
            for (int j = 0; j < 2; ++j)
                bb[j] = *(const bf16x8*)(K + (size_t)(k0 + wc * 32 + j * 16 + lr) * 256 + d0 + lk * 8);
#pragma unroll
            for (int i = 0; i < 4; ++i)
#pragma unroll
                for (int j = 0; j < 2; ++j)
                    sacc[i][j] = __builtin_amdgcn_mfma_f32_16x16x32_bf16(a[i], bb[j], sacc[i][j], 0, 0, 0);
        }
#pragma unroll
        for (int i = 0; i < 4; ++i)
#pragma unroll
            for (int j = 0; j < 2; ++j)
#pragma unroll
                for (int r = 0; r < 4; ++r)
                    Pl[wr * 64 + i * 16 + lk * 4 + r][wc * 32 + j * 16 + lr] =
                        (__bf16)__expf(sacc[i][j][r] * 0.0625f);
        __syncthreads();
#pragma unroll
        for (int ks = 0; ks < 2; ++ks) {
            bf16x8 a[4], bb[4];
#pragma unroll
            for (int i = 0; i < 4; ++i)
                a[i] = *(const bf16x8*)(&Pl[wr * 64 + i * 16 + lr][ks * 32 + lk * 8]);
#pragma unroll
            for (int j = 0; j < 4; ++j)
                bb[j] = *(const bf16x8*)(V + (size_t)(vbase + wc * 64 + j * 16 + lr) * ROWS + k0 + ks * 32 + lk * 8);
#pragma unroll
            for (int i = 0; i < 4; ++i)
#pragma unroll
                for (int j = 0; j < 4; ++j)
                    oacc[i][j] = __builtin_amdgcn_mfma_f32_16x16x32_bf16(a[i], bb[j], oacc[i][j], 0, 0, 0);
        }
        __syncthreads();
    }
    float* O = out + (size_t)b * SEQ * 256;
#pragma unroll
    for (int i = 0; i < 4; ++i)
#pragma unroll
        for (int j = 0; j < 4; ++j)
#pragma unroll
            for (int r = 0; r < 4; ++r) {
                int row = qbase + wr * 64 + i * 16 + lk * 4 + r;
                int col = vbase + wc * 64 + j * 16 + lr;
                O[(size_t)row * 256 + col] = oacc[i][j][r];
            }
}

extern "C" void kernel_launch(void* const* d_in, const int* in_sizes, int n_in,
                              void* d_out, int out_size, void* d_ws, size_t ws_size,
                              hipStream_t stream) {
    const float* x  = (const float*)d_in[0];
    const float* wq = (const float*)d_in[1];
    const float* wk = (const float*)d_in[2];
    const float* wv = (const float*)d_in[3];
    float* out = (float*)d_out;

    char* ws = (char*)d_ws;
    __bf16* Xb  = (__bf16*)(ws + 0);
    __bf16* Qb  = (__bf16*)(ws + 8388608);
    __bf16* Kb  = (__bf16*)(ws + 16777216);
    __bf16* Vt  = (__bf16*)(ws + 25165824);
    __bf16* Wqb = (__bf16*)(ws + 33554432);
    __bf16* Wkb = (__bf16*)(ws + 33685504);
    __bf16* Wvb = (__bf16*)(ws + 33816576);
    float*  lsum = (float*)(ws + 33947648);
    __bf16* Pbuf = (__bf16*)(ws + 34013184);
    const size_t need_A = 34013184 + (size_t)BATCH * SEQ * SEQ * 2;   // ~168 MB

    const int n_x = ROWS * DIM;      // 4194304

    cast_v8<<<(n_x / 8 + 255) / 256, 256, 0, stream>>>(x, Xb, n_x / 8);
    cast_w3<<<(3 * 8192 + 255) / 256, 256, 0, stream>>>(wq, wk, wv, Wqb, Wkb, Wvb);

    dim3 gg(ROWS / 128, DIM / 128, 3);   // (128, 2, 3)
    gemm_qkv<<<gg, 256, 0, stream>>>(Xb, Wqb, Wkb, Wvb, Qb, Kb, Vt);

    hipMemsetAsync(lsum, 0, (size_t)BATCH * SEQ * sizeof(float), stream);

    if (ws_size >= need_A) {
        dim3 gs(SEQ / 128, SEQ / 128, BATCH);   // (32, 32, 4)
        sp_kernel<<<gs, 256, 0, stream>>>(Qb, Kb, Pbuf, lsum);
        scale_vt<<<(n_x / 8 + 255) / 256, 256, 0, stream>>>(Vt, lsum, n_x / 8);
        pv_gemm<<<256, 512, 0, stream>>>(Pbuf, Vt, out);   // 128x128 tile, 8 waves
    } else {
        dim3 gs(SEQ / 128, 2, BATCH);
        colsumexp<<<gs, 256, 0, stream>>>(Qb, Kb, lsum);
        scale_vt<<<(n_x / 8 + 255) / 256, 256, 0, stream>>>(Vt, lsum, n_x / 8);
        dim3 gp(SEQ / 128, DIM / 128, BATCH);
        pv_kernel<<<gp, 256, 0, stream>>>(Qb, Kb, Vt, out);
    }
}